// Round 1
// baseline (15.588 us; speedup 1.0000x reference)
//
#include <hip/hip_runtime.h>
#include <math.h>

#define BB 2
#define SS 256
#define DD 256
#define EPSF 1e-6f

__device__ __forceinline__ float block_reduce_sum(float v, float* lds) {
    int t = threadIdx.x;
    lds[t] = v;
    __syncthreads();
    for (int s = 128; s > 0; s >>= 1) {
        if (t < s) lds[t] += lds[t + s];
        __syncthreads();
    }
    float r = lds[0];
    __syncthreads();
    return r;
}

// Kernel 1: per (b,s) row LayerNorm + dots with w1,w2.
__global__ void ln_dots_kernel(const float* __restrict__ ctx,
                               const float* __restrict__ ln_g,
                               const float* __restrict__ ln_b,
                               const float* __restrict__ fc_w,
                               float* __restrict__ dx1,
                               float* __restrict__ dx2) {
    __shared__ float lds[DD];
    const int r = blockIdx.x;   // b*S + s
    const int t = threadIdx.x;  // d
    const float c = ctx[r * DD + t];
    const float mu = block_reduce_sum(c, lds) * (1.0f / DD);
    const float dmu = c - mu;
    const float var = block_reduce_sum(dmu * dmu, lds) * (1.0f / (DD - 1));
    const float xn = ln_g[t] * dmu / (sqrtf(var) + EPSF) + ln_b[t];
    const float s1 = block_reduce_sum(xn * fc_w[t], lds);
    const float s2 = block_reduce_sum(xn * fc_w[DD + t], lds);
    if (t == 0) { dx1[r] = s1; dx2[r] = s2; }
}

// Kernel 2: inclusive scan of dx2 per batch -> P2[b][0..S] with P2[b][0]=0.
__global__ void scan_kernel(const float* __restrict__ dx2, float* __restrict__ P2) {
    __shared__ float lds[SS];
    const int b = blockIdx.x, t = threadIdx.x;
    lds[t] = dx2[b * SS + t];
    __syncthreads();
    for (int o = 1; o < SS; o <<= 1) {
        float add = (t >= o) ? lds[t - o] : 0.0f;
        __syncthreads();
        lds[t] += add;
        __syncthreads();
    }
    P2[b * (SS + 1) + t + 1] = lds[t];
    if (t == 0) P2[b * (SS + 1)] = 0.0f;
}

// Kernel 3: per (b,i) row: Mij + product-scan -> symmetric G.
__global__ void mij_g_kernel(const float* __restrict__ dx1,
                             const float* __restrict__ P2,
                             const float* __restrict__ prior,
                             const float* __restrict__ fc_b,
                             float* __restrict__ G,
                             float* __restrict__ Mij) {
    __shared__ float lds[SS];
    const int r = blockIdx.x;        // b*S + i
    const int b = r / SS, i = r % SS;
    const int k = threadIdx.x;
    const float pr = prior[0], fb = fc_b[0];
    float m;
    if (k >= i) {
        const float base = P2[b * (SS + 1) + i];
        const float l = dx1[b * SS + k]
                      + (P2[b * (SS + 1) + k + 1] - base) / (float)(k - i + 1)
                      + fb;
        m = pr + (1.0f - pr) / (1.0f + expf(-l));
    } else {
        m = pr + (1.0f - pr) / (1.0f + expf(-fb));
    }
    Mij[r * SS + k] = m;

    // inclusive product scan of v = (k>=i) ? m : 1
    lds[k] = (k >= i) ? m : 1.0f;
    __syncthreads();
    for (int o = 1; o < SS; o <<= 1) {
        float mul = (k >= o) ? lds[k - o] : 1.0f;
        __syncthreads();
        lds[k] *= mul;
        __syncthreads();
    }
    const float p = lds[k];

    if (k == i) {
        G[(b * SS + i) * SS + i] = 1.0f;
    } else if (k > i) {
        G[(b * SS + i) * SS + k] = p;       // upper triangle (row write)
        G[(b * SS + k) * SS + i] = p;       // symmetric lower element
    }
}

extern "C" void kernel_launch(void* const* d_in, const int* in_sizes, int n_in,
                              void* d_out, int out_size, void* d_ws, size_t ws_size,
                              hipStream_t stream) {
    const float* ctx   = (const float*)d_in[0];
    // d_in[1] = eos_mask (unused by reference)
    const float* prior = (const float*)d_in[2];
    const float* ln_g  = (const float*)d_in[3];
    const float* ln_b  = (const float*)d_in[4];
    const float* fc_w  = (const float*)d_in[5];
    const float* fc_b  = (const float*)d_in[6];

    float* G   = (float*)d_out;                       // B*S*S
    float* Mij = (float*)d_out + BB * SS * SS;        // B*S*S

    float* dx1 = (float*)d_ws;                        // B*S
    float* dx2 = dx1 + BB * SS;                       // B*S
    float* P2  = dx2 + BB * SS;                       // B*(S+1)

    ln_dots_kernel<<<BB * SS, DD, 0, stream>>>(ctx, ln_g, ln_b, fc_w, dx1, dx2);
    scan_kernel<<<BB, SS, 0, stream>>>(dx2, P2);
    mij_g_kernel<<<BB * SS, SS, 0, stream>>>(dx1, P2, prior, fc_b, G, Mij);
}